// Round 11
// baseline (934.951 us; speedup 1.0000x reference)
//
#include <hip/hip_runtime.h>
#include <hip/hip_bf16.h>

#define NUM_ADC_P 8
#define DENSE_L   1024
#define L_TILDE   64

#define M_PER_BLOCK 512                   // rows per block (16 waves x 32 rows)
#define THREADS     1024
#define N_PASSES    3                     // DIAGNOSTIC: 3 identical passes

typedef __attribute__((ext_vector_type(8))) short  short8;   // 8 bf16 (MFMA A/B frag)
typedef __attribute__((ext_vector_type(4))) float  float4v;  // MFMA C/D frag

// ---------------------------------------------------------------------------
// DIAGNOSTIC ROUND. R10 (this structure, single-pass) = 703.2 us => G ~ 125
// us = 76% of the ~90 us HBM floor. Remaining theories for the 25% need gemm
// counters, never yet observed (gemm hides below the 333-us harness fills in
// top-5). This kernel = R10 mega-kernel (Wt in swizzled LDS, A-only vmcnt
// FIFO, depth-2 reg prefetch) wrapped in a 3x pass loop:
//   - one ~375-us dispatch SURFACES in the top-5 counter rows ->
//     FETCH_SIZE / VGPR_Count / Occupancy / MfmaUtil / VALUBusy / BANK_CONF.
//   - per-pass time cross-checks G: G = (dur - ~578.5)/3.
//   - zoff (runtime 0, opaque to codegen) makes pass bodies formally
//     distinct -> no CSE/DSE across passes; out written 3x idempotently.
//
// Fragment layout (verified, absmax 0.125):
//   A frag: lane holds A[m0 + (lane&15)][32*kk + (lane>>4)*8 + j], j=0..7
//   B frag: lane holds Wt[n0 + (lane&15)][32*kk + (lane>>4)*8 + j]
//   D frag: D[m0 + (lane>>4)*4 + rr][n0 + (lane&15)], rr=0..3
// ---------------------------------------------------------------------------

__device__ __forceinline__ short8 cvt8(float4v a, float4v b) {
    union { short8 s; __hip_bfloat162 h[4]; } u;
    u.h[0] = __float22bfloat162_rn(make_float2(a[0], a[1]));
    u.h[1] = __float22bfloat162_rn(make_float2(a[2], a[3]));
    u.h[2] = __float22bfloat162_rn(make_float2(b[0], b[1]));
    u.h[3] = __float22bfloat162_rn(make_float2(b[2], b[3]));
    return u.s;
}

__device__ __forceinline__ float4v ldnt(const float* p) {
    return __builtin_nontemporal_load((const float4v*)p);
}

__global__ __launch_bounds__(THREADS, 4)
void sampling_gemm(const float* __restrict__ x,
                   const float* __restrict__ weight,
                   float* __restrict__ out,
                   long zoff) {                    // runtime 0; defeats CSE
    __shared__ short Wt[64 * DENSE_L];            // 128 KiB, swizzled bf16
    char* wtb = (char*)Wt;

    const int tid = threadIdx.x;

    // ---- Wt init: thread (n = tid>>4) covers k in [ (tid&15)*64, +64 ) ----
    {
        const int n  = tid >> 4;                  // 0..63
        const int k0 = (tid & 15) * 64;
        const float wn = weight[n];
        const int xr = (n & 7) << 4;
        #pragma unroll 8
        for (int j = 0; j < 64; ++j) {
            const int k = k0 + j;
            const float d = (float)(k + 1) - wn;
            const int byte = (n * 2048 + k * 2) ^ xr;
            *(__hip_bfloat16*)(wtb + byte) = __float2bfloat16(expf(-d * d * 0.01f));
        }
    }
    __syncthreads();                              // the ONLY barrier

    const int lane = tid & 63;
    const int wave = tid >> 6;                    // 0..15
    const int r    = lane & 15;
    const int q    = lane >> 4;                   // quad 0..3

    const long m0 = (long)blockIdx.x * M_PER_BLOCK + (long)wave * 32;

    // B-frag LDS addressing: lin(ns,kk) = (ns*16+r)*2048 + kk*64 + q*16,
    // read addr = lin ^ xmask (xmask = (r&7)<<4, matching the write side).
    const int xmask = (r & 7) << 4;
    const int bbase = r * 2048 + q * 16;

    for (int pass = 0; pass < N_PASSES; ++pass) {
        const float* xp = x   + (long)pass * zoff;   // zoff==0 at runtime
        float*       op = out + (long)pass * zoff;

        const float* a0 = xp + (m0 + r) * DENSE_L + q * 8;  // m-subtile 0 row
        const float* a1 = a0 + 16 * DENSE_L;                // m-subtile 1 row

        float4v acc[2][4];
        #pragma unroll
        for (int i = 0; i < 2; ++i)
            #pragma unroll
            for (int j = 0; j < 4; ++j)
                acc[i][j] = (float4v){0.f, 0.f, 0.f, 0.f};

        // prologue: E = slab 0, O = slab 1 (depth-2, A-only vmcnt FIFO)
        float4v e0a = ldnt(a0),      e0b = ldnt(a0 + 4);
        float4v e1a = ldnt(a1),      e1b = ldnt(a1 + 4);
        float4v o0a = ldnt(a0 + 32), o0b = ldnt(a0 + 36);
        float4v o1a = ldnt(a1 + 32), o1b = ldnt(a1 + 36);

        // consume slabs t,t+1; prefetch t+2,t+3 (covers 2..31 exactly)
        for (int t = 0; t < 30; t += 2) {
            { // even slab t: consume E (vmcnt counted: O still in flight)
                const short8 af0 = cvt8(e0a, e0b);
                const short8 af1 = cvt8(e1a, e1b);
                e0a = ldnt(a0 + (t + 2) * 32); e0b = ldnt(a0 + (t + 2) * 32 + 4);
                e1a = ldnt(a1 + (t + 2) * 32); e1b = ldnt(a1 + (t + 2) * 32 + 4);
                #pragma unroll
                for (int ns = 0; ns < 4; ++ns) {
                    const short8 bf = *(const short8*)(
                        wtb + ((bbase + ns * 32768 + t * 64) ^ xmask));
                    acc[0][ns] = __builtin_amdgcn_mfma_f32_16x16x32_bf16(af0, bf, acc[0][ns], 0, 0, 0);
                    acc[1][ns] = __builtin_amdgcn_mfma_f32_16x16x32_bf16(af1, bf, acc[1][ns], 0, 0, 0);
                }
            }
            { // odd slab t+1: consume O (new E in flight)
                const short8 af0 = cvt8(o0a, o0b);
                const short8 af1 = cvt8(o1a, o1b);
                o0a = ldnt(a0 + (t + 3) * 32); o0b = ldnt(a0 + (t + 3) * 32 + 4);
                o1a = ldnt(a1 + (t + 3) * 32); o1b = ldnt(a1 + (t + 3) * 32 + 4);
                #pragma unroll
                for (int ns = 0; ns < 4; ++ns) {
                    const short8 bf = *(const short8*)(
                        wtb + ((bbase + ns * 32768 + (t + 1) * 64) ^ xmask));
                    acc[0][ns] = __builtin_amdgcn_mfma_f32_16x16x32_bf16(af0, bf, acc[0][ns], 0, 0, 0);
                    acc[1][ns] = __builtin_amdgcn_mfma_f32_16x16x32_bf16(af1, bf, acc[1][ns], 0, 0, 0);
                }
            }
        }
        { // epilogue slab 30 (E)
            const short8 af0 = cvt8(e0a, e0b);
            const short8 af1 = cvt8(e1a, e1b);
            #pragma unroll
            for (int ns = 0; ns < 4; ++ns) {
                const short8 bf = *(const short8*)(
                    wtb + ((bbase + ns * 32768 + 30 * 64) ^ xmask));
                acc[0][ns] = __builtin_amdgcn_mfma_f32_16x16x32_bf16(af0, bf, acc[0][ns], 0, 0, 0);
                acc[1][ns] = __builtin_amdgcn_mfma_f32_16x16x32_bf16(af1, bf, acc[1][ns], 0, 0, 0);
            }
        }
        { // epilogue slab 31 (O)
            const short8 af0 = cvt8(o0a, o0b);
            const short8 af1 = cvt8(o1a, o1b);
            #pragma unroll
            for (int ns = 0; ns < 4; ++ns) {
                const short8 bf = *(const short8*)(
                    wtb + ((bbase + ns * 32768 + 31 * 64) ^ xmask));
                acc[0][ns] = __builtin_amdgcn_mfma_f32_16x16x32_bf16(af0, bf, acc[0][ns], 0, 0, 0);
                acc[1][ns] = __builtin_amdgcn_mfma_f32_16x16x32_bf16(af1, bf, acc[1][ns], 0, 0, 0);
            }
        }

        // Stores: D[m0 + ms*16 + q*4 + rr][ns*16 + r]; streaming, idempotent
        // across passes (identical values).
        #pragma unroll
        for (int ms = 0; ms < 2; ++ms) {
            #pragma unroll
            for (int ns = 0; ns < 4; ++ns) {
                #pragma unroll
                for (int rr = 0; rr < 4; ++rr) {
                    __builtin_nontemporal_store(
                        acc[ms][ns][rr],
                        op + (m0 + ms * 16 + q * 4 + rr) * L_TILDE + ns * 16 + r);
                }
            }
        }
    }
}

// ---------------------------------------------------------------------------
extern "C" void kernel_launch(void* const* d_in, const int* in_sizes, int n_in,
                              void* d_out, int out_size, void* d_ws, size_t ws_size,
                              hipStream_t stream) {
    const float* x      = (const float*)d_in[0];   // [B, P*L] fp32
    const float* weight = (const float*)d_in[1];   // [64] fp32
    float* out          = (float*)d_out;           // [B, P*64] fp32
    (void)d_ws; (void)ws_size;                     // workspace unused

    const int M = in_sizes[0] / DENSE_L;           // B * NUM_ADC_P = 131072
    const int grid = M / M_PER_BLOCK;              // 256 blocks = 1/CU

    sampling_gemm<<<grid, THREADS, 0, stream>>>(x, weight, out, 0L);
}